// Round 14
// baseline (245.565 us; speedup 1.0000x reference)
//
#include <hip/hip_runtime.h>
#include <math.h>

#define B 8
#define S 2048
#define D_MODEL 512
#define NK 256      // n_kernels (conv out channels / attention feature dim)
#define KSZ 9
#define NC 4096     // n_classes
#define PADW 4
#define SSPLIT 8    // attention s-dimension split
#define CM 64       // conv s-rows per block
#define CW (CM + 8) // staged window rows (72)
#define NSTG (KSZ * 16)                // 144 K-stages: stg = t*16 + h (h = 32-d chunk)
#define NTILES ((S / SSPLIT) / 32)     // 8 x-tiles per attn block

typedef __attribute__((ext_vector_type(8))) short bf16x8;
typedef __attribute__((ext_vector_type(4))) float f32x4;

static __device__ __forceinline__ unsigned short f2bf(float f) {
    unsigned int u = __float_as_uint(f);
    unsigned int r = (u + 0x7fffu + ((u >> 16) & 1u)) >> 16;
    return (unsigned short)r;
}

#define GLOAD_LDS16(g, l) __builtin_amdgcn_global_load_lds( \
    (const __attribute__((address_space(1))) void*)(g),     \
    (__attribute__((address_space(3))) void*)(l), 16, 0, 0)

// ---- fused prep: conv_w -> wtb [stg][k][d32] bf16 (stage-contig 16KB);
// ---- U (pre-scaled by log2e) / F fp32 -> bf16, 4 elems/thread vectorized --
#define PREP_W (KSZ * NK * D_MODEL)
#define PREP_UF (NC * NK)
#define PREP_N (PREP_W + (2 * PREP_UF) / 4)
__global__ __launch_bounds__(256) void prep_all(
    const float* __restrict__ w, unsigned short* __restrict__ wtb,
    const float* __restrict__ U, unsigned short* __restrict__ Ub,
    const float* __restrict__ F, unsigned short* __restrict__ Fb)
{
    const float LOG2E = 1.44269504088896340736f;
    int idx = blockIdx.x * 256 + threadIdx.x;
    if (idx < PREP_W) {
        int dd  = idx & 31;
        int k   = (idx >> 5) & (NK - 1);
        int stg = idx >> 13;              // / (32*NK)
        int t = stg >> 4, h = stg & 15;
        wtb[idx] = f2bf(w[((size_t)k * D_MODEL + h * 32 + dd) * KSZ + t]);
        return;
    }
    idx -= PREP_W;
    if (idx < PREP_UF / 4) {
        float4 v = ((const float4*)U)[idx];
        ushort4 o;
        o.x = f2bf(v.x * LOG2E); o.y = f2bf(v.y * LOG2E);
        o.z = f2bf(v.z * LOG2E); o.w = f2bf(v.w * LOG2E);
        ((ushort4*)Ub)[idx] = o;
        return;
    }
    idx -= PREP_UF / 4;
    if (idx < PREP_UF / 4) {
        float4 v = ((const float4*)F)[idx];
        ushort4 o;
        o.x = f2bf(v.x); o.y = f2bf(v.y);
        o.z = f2bf(v.z); o.w = f2bf(v.w);
        ((ushort4*)Fb)[idx] = o;
    }
}

// ---- embed-gather + MFMA conv1d + bias + tanh -> xf bf16 [b][s][k] --------
// M-split variant of the r8 structure: 8 waves, wave tile M32 x N64.
// Waves 0-3 take rows 0-31 (N-slices 0-3), waves 4-7 rows 32-63 — A-side
// ds_read_b128 count HALVES vs M64xN32 (2/stage/wave); B-reads double but
// wave-pairs (wv, wv+4) hit identical B addresses -> L1-absorbed.
// Window staged once, ONE barrier, depth-3 static software pipeline.
__global__ __launch_bounds__(512, 2) void conv_mfma(
    const int* __restrict__ text, const float* __restrict__ emb,
    const unsigned short* __restrict__ wtb, const float* __restrict__ bias,
    unsigned short* __restrict__ xf)
{
    __shared__ unsigned short xs[CW * D_MODEL];   // 73,728 B
    const int b  = blockIdx.x >> 5;               // S/CM = 32 s-blocks
    const int s0 = (blockIdx.x & 31) * CM;
    const int tid = threadIdx.x;

    for (int u = tid; u < CW * 64; u += 512) {
        int row = u >> 6, c = u & 63;             // c = logical 16B chunk
        int gs = s0 + row - PADW;
        float4 v0 = make_float4(0.f, 0.f, 0.f, 0.f), v1 = v0;
        if (gs >= 0 && gs < S) {
            int tok = text[b * S + gs];
            const float4* e4 = (const float4*)(emb + (size_t)tok * D_MODEL + c * 8);
            v0 = e4[0]; v1 = e4[1];
        }
        union { bf16x8 v; unsigned short us[8]; } pk;
        pk.us[0] = f2bf(v0.x); pk.us[1] = f2bf(v0.y);
        pk.us[2] = f2bf(v0.z); pk.us[3] = f2bf(v0.w);
        pk.us[4] = f2bf(v1.x); pk.us[5] = f2bf(v1.y);
        pk.us[6] = f2bf(v1.z); pk.us[7] = f2bf(v1.w);
        int phys = c ^ (row & 7);
        *(bf16x8*)(xs + row * D_MODEL + phys * 8) = pk.v;
    }
    __syncthreads();                              // the ONLY barrier

    const int wv   = tid >> 6;                    // 0..7
    const int lane = tid & 63;
    const int cl   = lane & 15;
    const int quad = lane >> 4;
    const int mg   = wv >> 2;                     // m-group: rows mg*32 ..
    const int n0   = (wv & 3) * 64;               // 4 n-slices of 64 channels

    bf16x8 A0[2], A1[2], A2[2];
    bf16x8 B0[4], B1[4], B2[4];
    f32x4 acc[2][4] = {};

    #define LDB(BB, stg)                                                      \
        {                                                                     \
            const unsigned short* wp = wtb + (size_t)(stg) * (NK * 32)        \
                                       + (n0 + cl) * 32 + quad * 8;           \
            BB[0] = *(const bf16x8*)(wp);                                     \
            BB[1] = *(const bf16x8*)(wp + 16 * 32);                           \
            BB[2] = *(const bf16x8*)(wp + 32 * 32);                           \
            BB[3] = *(const bf16x8*)(wp + 48 * 32);                           \
        }
    #define LDA(AA, stg)                                                      \
        {                                                                     \
            int t_ = (stg) >> 4, h_ = (stg) & 15;                             \
            _Pragma("unroll")                                                 \
            for (int ms = 0; ms < 2; ms++) {                                  \
                int row = mg * 32 + cl + ms * 16 + t_;                        \
                int ph  = (h_ * 4 + quad) ^ (row & 7);                        \
                AA[ms] = *(const bf16x8*)(xs + row * D_MODEL + ph * 8);       \
            }                                                                 \
        }
    #define FENCE asm volatile("" ::: "memory");
    #define DOMFMA(AA, BB)                                                    \
        _Pragma("unroll")                                                     \
        for (int ms = 0; ms < 2; ms++) {                                      \
            _Pragma("unroll")                                                 \
            for (int ns = 0; ns < 4; ns++)                                    \
                acc[ms][ns] = __builtin_amdgcn_mfma_f32_16x16x32_bf16(AA[ms], BB[ns], acc[ms][ns], 0, 0, 0); \
        }

    LDB(B0, 0) LDA(A0, 0) LDB(B1, 1) LDA(A1, 1) LDB(B2, 2) LDA(A2, 2) FENCE

    for (int ss = 0; ss < NSTG; ss += 3) {        // 48 iters
        DOMFMA(A0, B0)
        if (ss + 3 < NSTG) { LDB(B0, ss + 3) LDA(A0, ss + 3) FENCE }
        DOMFMA(A1, B1)
        if (ss + 4 < NSTG) { LDB(B1, ss + 4) LDA(A1, ss + 4) FENCE }
        DOMFMA(A2, B2)
        if (ss + 5 < NSTG) { LDB(B2, ss + 5) LDA(A2, ss + 5) FENCE }
    }

    // epilogue: bias + tanh -> bf16. C-layout: s=mg*32+ms*16+quad*4+r, k=n0+ns*16+cl
    #pragma unroll
    for (int ns = 0; ns < 4; ns++) {
        const int k = n0 + ns * 16 + cl;
        const float bk = bias[k];
        #pragma unroll
        for (int ms = 0; ms < 2; ms++) {
            #pragma unroll
            for (int r = 0; r < 4; r++) {
                int s = s0 + mg * 32 + ms * 16 + quad * 4 + r;
                float v = acc[ms][ns][r] + bk;
                float e = __expf(2.f * v);
                float th = 1.f - 2.f / (e + 1.f); // tanh(v)
                xf[((size_t)b * S + s) * NK + k] = f2bf(th);
            }
        }
    }
}

// -------- MFMA attention: max-free softmax, bf16 U/F tables (r10 proven) ---
__global__ __launch_bounds__(256, 2) void attn_mfma(
    const unsigned short* __restrict__ xf, const unsigned short* __restrict__ Ub,
    const unsigned short* __restrict__ Fb, float* __restrict__ pl,
    float* __restrict__ pg)
{
    __shared__ unsigned short xsa[2 * 32 * NK];   // 2 x 16 KB
    const int b    = blockIdx.z;
    const int sp   = blockIdx.y;
    const int tid  = threadIdx.x;
    const int wv   = tid >> 6;
    const int lane = tid & 63;
    const int cl   = lane & 15;
    const int quad = lane >> 4;
    const int c0   = blockIdx.x * 128 + wv * 32;
    const int wvu  = __builtin_amdgcn_readfirstlane(wv);

    bf16x8 uf[2][8], ff[2][8];
    #pragma unroll
    for (int cg = 0; cg < 2; cg++) {
        const unsigned short* up = Ub + (size_t)(c0 + cg * 16 + cl) * NK + quad * 8;
        const unsigned short* fp = Fb + (size_t)(c0 + cg * 16 + cl) * NK + quad * 8;
        #pragma unroll
        for (int kk = 0; kk < 8; kk++) {
            uf[cg][kk] = *(const bf16x8*)(up + kk * 32);
            ff[cg][kk] = *(const bf16x8*)(fp + kk * 32);
        }
    }

    const int sbeg = sp * (S / SSPLIT);
    const unsigned short* xb = xf + ((size_t)b * S + sbeg) * NK;

    #define STAGE(bb, t)                                                      \
        {                                                                     \
            _Pragma("unroll")                                                 \
            for (int j = 0; j < 4; j++) {                                     \
                int C = j * 256 + tid;                                        \
                int r = C >> 5, p = C & 31;                                   \
                int jl = p ^ (r & 7);                                         \
                const unsigned short* src = xb + (size_t)((t) * 32 + r) * NK + jl * 8; \
                unsigned short* dst = xsa + (bb) * 8192 + j * 2048 + wvu * 512; \
                GLOAD_LDS16(src, dst);                                        \
            }                                                                 \
        }

    STAGE(0, 0)

    float l[2] = {0.f, 0.f}, G[2] = {0.f, 0.f};
    const int swz = cl & 7;

    for (int t = 0; t < NTILES; t++) {
        __syncthreads();
        if (t + 1 < NTILES) STAGE((t + 1) & 1, t + 1)

        const unsigned short* bs = xsa + (t & 1) * 8192;
        f32x4 sa[2][2] = {}, ga[2][2] = {};       // [rowgrp][cg]
        #pragma unroll
        for (int kk = 0; kk < 8; kk++) {
            int p0 = (quad + 4 * kk) ^ swz;
            bf16x8 a0 = *(const bf16x8*)(bs + cl * NK + p0 * 8);
            bf16x8 a1 = *(const bf16x8*)(bs + (16 + cl) * NK + p0 * 8);
            #pragma unroll
            for (int cg = 0; cg < 2; cg++) {
                sa[0][cg] = __builtin_amdgcn_mfma_f32_16x16x32_bf16(a0, uf[cg][kk], sa[0][cg], 0, 0, 0);
                ga[0][cg] = __builtin_amdgcn_mfma_f32_16x16x32_bf16(a0, ff[cg][kk], ga[0][cg], 0, 0, 0);
                sa[1][cg] = __builtin_amdgcn_mfma_f32_16x16x32_bf16(a1, uf[cg][kk], sa[1][cg], 0, 0, 0);
                ga[1][cg] = __builtin_amdgcn_mfma_f32_16x16x32_bf16(a1, ff[cg][kk], ga[1][cg], 0, 0, 0);
            }
        }

        // max-free softmax accumulation (straight-line)
        #pragma unroll
        for (int cg = 0; cg < 2; cg++) {
            #pragma unroll
            for (int r = 0; r < 4; r++) {
                float e0 = exp2f(sa[0][cg][r]);
                float e1 = exp2f(sa[1][cg][r]);
                l[cg] += e0 + e1;
                G[cg] += e0 * ga[0][cg][r] + e1 * ga[1][cg][r];
            }
        }
    }

    #pragma unroll
    for (int cg = 0; cg < 2; cg++) {
        l[cg] += __shfl_xor(l[cg], 16); l[cg] += __shfl_xor(l[cg], 32);
        G[cg] += __shfl_xor(G[cg], 16); G[cg] += __shfl_xor(G[cg], 32);
    }
    if (lane < 16) {
        #pragma unroll
        for (int cg = 0; cg < 2; cg++) {
            size_t idx = ((size_t)b * SSPLIT + sp) * NC + c0 + cg * 16 + lane;
            pl[idx] = l[cg]; pg[idx] = G[cg];
        }
    }
}

// -------- combine S-split partials + bias -> y [b][c] ----------------------
__global__ __launch_bounds__(256) void combine_kernel(
    const float* __restrict__ pl, const float* __restrict__ pg,
    const float* __restrict__ fb, float* __restrict__ out)
{
    int idx = blockIdx.x * 256 + threadIdx.x;     // over B*NC
    if (idx >= B * NC) return;
    int b = idx / NC, c = idx % NC;
    float l = 0.f, g = 0.f;
    #pragma unroll
    for (int sp = 0; sp < SSPLIT; sp++) {
        size_t i = ((size_t)b * SSPLIT + sp) * NC + c;
        l += pl[i];
        g += pg[i];
    }
    out[idx] = g / l + fb[c];
}

extern "C" void kernel_launch(void* const* d_in, const int* in_sizes, int n_in,
                              void* d_out, int out_size, void* d_ws, size_t ws_size,
                              hipStream_t stream) {
    const int*   text   = (const int*)  d_in[0];
    const float* emb    = (const float*)d_in[1];
    const float* conv_w = (const float*)d_in[2];
    const float* conv_b = (const float*)d_in[3];
    const float* U_w    = (const float*)d_in[4];
    const float* F_w    = (const float*)d_in[5];
    const float* f_b    = (const float*)d_in[6];
    float* out = (float*)d_out;

    char* ws = (char*)d_ws;
    unsigned short* xf  = (unsigned short*)ws; ws += (size_t)B * S * NK * 2;
    unsigned short* wtb = (unsigned short*)ws; ws += (size_t)KSZ * NK * D_MODEL * 2;
    unsigned short* Ub  = (unsigned short*)ws; ws += (size_t)NC * NK * 2;
    unsigned short* Fb  = (unsigned short*)ws; ws += (size_t)NC * NK * 2;
    float* pl = (float*)ws; ws += (size_t)SSPLIT * B * NC * 4;
    float* pg = (float*)ws; ws += (size_t)SSPLIT * B * NC * 4;

    prep_all<<<dim3((PREP_N + 255) / 256), 256, 0, stream>>>(conv_w, wtb, U_w, Ub, F_w, Fb);
    conv_mfma<<<dim3(B * S / CM), 512, 0, stream>>>(text, emb, wtb, conv_b, xf);
    attn_mfma<<<dim3(NC / 128, SSPLIT, B), 256, 0, stream>>>(xf, Ub, Fb, pl, pg);
    combine_kernel<<<dim3((B * NC + 255) / 256), 256, 0, stream>>>(pl, pg, f_b, out);
}

// Round 15
// 211.826 us; speedup vs baseline: 1.1593x; 1.1593x over previous
//
#include <hip/hip_runtime.h>
#include <math.h>

#define B 8
#define S 2048
#define D_MODEL 512
#define NK 256      // n_kernels (conv out channels / attention feature dim)
#define KSZ 9
#define NC 4096     // n_classes
#define PADW 4
#define SSPLIT 4    // attention s-dimension split
#define CM 64       // conv s-rows per block
#define CW (CM + 8) // staged window rows (72)
#define NSTG (KSZ * 16)                // 144 K-stages: stg = t*16 + h (h = 32-d chunk)
#define NTILES ((S / SSPLIT) / 32)     // 16 x-tiles per attn block

typedef __attribute__((ext_vector_type(8))) short bf16x8;
typedef __attribute__((ext_vector_type(4))) float f32x4;

static __device__ __forceinline__ unsigned short f2bf(float f) {
    unsigned int u = __float_as_uint(f);
    unsigned int r = (u + 0x7fffu + ((u >> 16) & 1u)) >> 16;
    return (unsigned short)r;
}

#define GLOAD_LDS16(g, l) __builtin_amdgcn_global_load_lds( \
    (const __attribute__((address_space(1))) void*)(g),     \
    (__attribute__((address_space(3))) void*)(l), 16, 0, 0)

// ---- fused prep: conv_w -> wtb [stg][k][d32] bf16 (stage-contig 16KB);
// ---- U (pre-scaled by log2e) / F fp32 -> bf16, 4 elems/thread vectorized --
#define PREP_W (KSZ * NK * D_MODEL)
#define PREP_UF (NC * NK)
#define PREP_N (PREP_W + (2 * PREP_UF) / 4)
__global__ __launch_bounds__(256) void prep_all(
    const float* __restrict__ w, unsigned short* __restrict__ wtb,
    const float* __restrict__ U, unsigned short* __restrict__ Ub,
    const float* __restrict__ F, unsigned short* __restrict__ Fb)
{
    const float LOG2E = 1.44269504088896340736f;
    int idx = blockIdx.x * 256 + threadIdx.x;
    if (idx < PREP_W) {
        int dd  = idx & 31;
        int k   = (idx >> 5) & (NK - 1);
        int stg = idx >> 13;              // / (32*NK)
        int t = stg >> 4, h = stg & 15;
        wtb[idx] = f2bf(w[((size_t)k * D_MODEL + h * 32 + dd) * KSZ + t]);
        return;
    }
    idx -= PREP_W;
    if (idx < PREP_UF / 4) {
        float4 v = ((const float4*)U)[idx];
        ushort4 o;
        o.x = f2bf(v.x * LOG2E); o.y = f2bf(v.y * LOG2E);
        o.z = f2bf(v.z * LOG2E); o.w = f2bf(v.w * LOG2E);
        ((ushort4*)Ub)[idx] = o;
        return;
    }
    idx -= PREP_UF / 4;
    if (idx < PREP_UF / 4) {
        float4 v = ((const float4*)F)[idx];
        ushort4 o;
        o.x = f2bf(v.x); o.y = f2bf(v.y);
        o.z = f2bf(v.z); o.w = f2bf(v.w);
        ((ushort4*)Fb)[idx] = o;
    }
}

// ---- embed-gather + MFMA conv1d + bias + tanh -> xf bf16 [b][s][k] --------
// (round-8 proven optimum: window staged once, ONE barrier, depth-3 static
// software pipeline, 8 waves M64xN32, stage-contiguous weight stream.
// Variants tested and regressed: 32x32 shape (r11), M64xN64 @1 wave/SIMD
// (r12), M32xN64 8-wave (r14, compiler collapses pipeline to VGPR=56).)
__global__ __launch_bounds__(512, 2) void conv_mfma(
    const int* __restrict__ text, const float* __restrict__ emb,
    const unsigned short* __restrict__ wtb, const float* __restrict__ bias,
    unsigned short* __restrict__ xf)
{
    __shared__ unsigned short xs[CW * D_MODEL];   // 73,728 B
    const int b  = blockIdx.x >> 5;               // S/CM = 32 s-blocks
    const int s0 = (blockIdx.x & 31) * CM;
    const int tid = threadIdx.x;

    for (int u = tid; u < CW * 64; u += 512) {
        int row = u >> 6, c = u & 63;             // c = logical 16B chunk
        int gs = s0 + row - PADW;
        float4 v0 = make_float4(0.f, 0.f, 0.f, 0.f), v1 = v0;
        if (gs >= 0 && gs < S) {
            int tok = text[b * S + gs];
            const float4* e4 = (const float4*)(emb + (size_t)tok * D_MODEL + c * 8);
            v0 = e4[0]; v1 = e4[1];
        }
        union { bf16x8 v; unsigned short us[8]; } pk;
        pk.us[0] = f2bf(v0.x); pk.us[1] = f2bf(v0.y);
        pk.us[2] = f2bf(v0.z); pk.us[3] = f2bf(v0.w);
        pk.us[4] = f2bf(v1.x); pk.us[5] = f2bf(v1.y);
        pk.us[6] = f2bf(v1.z); pk.us[7] = f2bf(v1.w);
        int phys = c ^ (row & 7);
        *(bf16x8*)(xs + row * D_MODEL + phys * 8) = pk.v;
    }
    __syncthreads();                              // the ONLY barrier

    const int wv   = tid >> 6;                    // 0..7
    const int lane = tid & 63;
    const int cl   = lane & 15;
    const int quad = lane >> 4;
    const int n0   = wv * 32;                     // 8 waves cover 256 channels

    bf16x8 A0[4], A1[4], A2[4], B0[2], B1[2], B2[2];
    f32x4 acc[4][2] = {};

    #define LDB(BB, stg)                                                      \
        {                                                                     \
            const unsigned short* wp = wtb + (size_t)(stg) * (NK * 32)        \
                                       + (n0 + cl) * 32 + quad * 8;           \
            BB[0] = *(const bf16x8*)(wp);                                     \
            BB[1] = *(const bf16x8*)(wp + 16 * 32);                           \
        }
    #define LDA(AA, stg)                                                      \
        {                                                                     \
            int t_ = (stg) >> 4, h_ = (stg) & 15;                             \
            _Pragma("unroll")                                                 \
            for (int ms = 0; ms < 4; ms++) {                                  \
                int row = cl + ms * 16 + t_;                                  \
                int ph  = (h_ * 4 + quad) ^ (row & 7);                        \
                AA[ms] = *(const bf16x8*)(xs + row * D_MODEL + ph * 8);       \
            }                                                                 \
        }
    #define FENCE asm volatile("" ::: "memory");
    #define DOMFMA(AA, BB)                                                    \
        _Pragma("unroll")                                                     \
        for (int ms = 0; ms < 4; ms++) {                                      \
            acc[ms][0] = __builtin_amdgcn_mfma_f32_16x16x32_bf16(AA[ms], BB[0], acc[ms][0], 0, 0, 0); \
            acc[ms][1] = __builtin_amdgcn_mfma_f32_16x16x32_bf16(AA[ms], BB[1], acc[ms][1], 0, 0, 0); \
        }

    LDB(B0, 0) LDA(A0, 0) LDB(B1, 1) LDA(A1, 1) LDB(B2, 2) LDA(A2, 2) FENCE

    for (int ss = 0; ss < NSTG; ss += 3) {        // 48 iters
        DOMFMA(A0, B0)
        if (ss + 3 < NSTG) { LDB(B0, ss + 3) LDA(A0, ss + 3) FENCE }
        DOMFMA(A1, B1)
        if (ss + 4 < NSTG) { LDB(B1, ss + 4) LDA(A1, ss + 4) FENCE }
        DOMFMA(A2, B2)
        if (ss + 5 < NSTG) { LDB(B2, ss + 5) LDA(A2, ss + 5) FENCE }
    }

    #pragma unroll
    for (int ns = 0; ns < 2; ns++) {
        const int k = n0 + ns * 16 + cl;
        const float bk = bias[k];
        #pragma unroll
        for (int ms = 0; ms < 4; ms++) {
            #pragma unroll
            for (int r = 0; r < 4; r++) {
                int s = s0 + ms * 16 + quad * 4 + r;
                float v = acc[ms][ns][r] + bk;
                float e = __expf(2.f * v);
                float th = 1.f - 2.f / (e + 1.f); // tanh(v)
                xf[((size_t)b * S + s) * NK + k] = f2bf(th);
            }
        }
    }
}

// -------- MFMA attention: max-free softmax, bf16 U/F tables (r10 proven) ---
__global__ __launch_bounds__(256, 2) void attn_mfma(
    const unsigned short* __restrict__ xf, const unsigned short* __restrict__ Ub,
    const unsigned short* __restrict__ Fb, float* __restrict__ pl,
    float* __restrict__ pg)
{
    __shared__ unsigned short xsa[2 * 32 * NK];   // 2 x 16 KB
    const int b    = blockIdx.z;
    const int sp   = blockIdx.y;
    const int tid  = threadIdx.x;
    const int wv   = tid >> 6;
    const int lane = tid & 63;
    const int cl   = lane & 15;
    const int quad = lane >> 4;
    const int c0   = blockIdx.x * 128 + wv * 32;
    const int wvu  = __builtin_amdgcn_readfirstlane(wv);

    bf16x8 uf[2][8], ff[2][8];
    #pragma unroll
    for (int cg = 0; cg < 2; cg++) {
        const unsigned short* up = Ub + (size_t)(c0 + cg * 16 + cl) * NK + quad * 8;
        const unsigned short* fp = Fb + (size_t)(c0 + cg * 16 + cl) * NK + quad * 8;
        #pragma unroll
        for (int kk = 0; kk < 8; kk++) {
            uf[cg][kk] = *(const bf16x8*)(up + kk * 32);
            ff[cg][kk] = *(const bf16x8*)(fp + kk * 32);
        }
    }

    const int sbeg = sp * (S / SSPLIT);
    const unsigned short* xb = xf + ((size_t)b * S + sbeg) * NK;

    #define STAGE(bb, t)                                                      \
        {                                                                     \
            _Pragma("unroll")                                                 \
            for (int j = 0; j < 4; j++) {                                     \
                int C = j * 256 + tid;                                        \
                int r = C >> 5, p = C & 31;                                   \
                int jl = p ^ (r & 7);                                         \
                const unsigned short* src = xb + (size_t)((t) * 32 + r) * NK + jl * 8; \
                unsigned short* dst = xsa + (bb) * 8192 + j * 2048 + wvu * 512; \
                GLOAD_LDS16(src, dst);                                        \
            }                                                                 \
        }

    STAGE(0, 0)

    float l[2] = {0.f, 0.f}, G[2] = {0.f, 0.f};
    const int swz = cl & 7;

    for (int t = 0; t < NTILES; t++) {
        __syncthreads();
        if (t + 1 < NTILES) STAGE((t + 1) & 1, t + 1)

        const unsigned short* bs = xsa + (t & 1) * 8192;
        f32x4 sa[2][2] = {}, ga[2][2] = {};       // [rowgrp][cg]
        #pragma unroll
        for (int kk = 0; kk < 8; kk++) {
            int p0 = (quad + 4 * kk) ^ swz;
            bf16x8 a0 = *(const bf16x8*)(bs + cl * NK + p0 * 8);
            bf16x8 a1 = *(const bf16x8*)(bs + (16 + cl) * NK + p0 * 8);
            #pragma unroll
            for (int cg = 0; cg < 2; cg++) {
                sa[0][cg] = __builtin_amdgcn_mfma_f32_16x16x32_bf16(a0, uf[cg][kk], sa[0][cg], 0, 0, 0);
                ga[0][cg] = __builtin_amdgcn_mfma_f32_16x16x32_bf16(a0, ff[cg][kk], ga[0][cg], 0, 0, 0);
                sa[1][cg] = __builtin_amdgcn_mfma_f32_16x16x32_bf16(a1, uf[cg][kk], sa[1][cg], 0, 0, 0);
                ga[1][cg] = __builtin_amdgcn_mfma_f32_16x16x32_bf16(a1, ff[cg][kk], ga[1][cg], 0, 0, 0);
            }
        }

        // max-free softmax accumulation (straight-line)
        #pragma unroll
        for (int cg = 0; cg < 2; cg++) {
            #pragma unroll
            for (int r = 0; r < 4; r++) {
                float e0 = exp2f(sa[0][cg][r]);
                float e1 = exp2f(sa[1][cg][r]);
                l[cg] += e0 + e1;
                G[cg] += e0 * ga[0][cg][r] + e1 * ga[1][cg][r];
            }
        }
    }

    #pragma unroll
    for (int cg = 0; cg < 2; cg++) {
        l[cg] += __shfl_xor(l[cg], 16); l[cg] += __shfl_xor(l[cg], 32);
        G[cg] += __shfl_xor(G[cg], 16); G[cg] += __shfl_xor(G[cg], 32);
    }
    if (lane < 16) {
        #pragma unroll
        for (int cg = 0; cg < 2; cg++) {
            size_t idx = ((size_t)b * SSPLIT + sp) * NC + c0 + cg * 16 + lane;
            pl[idx] = l[cg]; pg[idx] = G[cg];
        }
    }
}

// -------- combine S-split partials + bias -> y [b][c] ----------------------
__global__ __launch_bounds__(256) void combine_kernel(
    const float* __restrict__ pl, const float* __restrict__ pg,
    const float* __restrict__ fb, float* __restrict__ out)
{
    int idx = blockIdx.x * 256 + threadIdx.x;     // over B*NC
    if (idx >= B * NC) return;
    int b = idx / NC, c = idx % NC;
    float l = 0.f, g = 0.f;
    #pragma unroll
    for (int sp = 0; sp < SSPLIT; sp++) {
        size_t i = ((size_t)b * SSPLIT + sp) * NC + c;
        l += pl[i];
        g += pg[i];
    }
    out[idx] = g / l + fb[c];
}

extern "C" void kernel_launch(void* const* d_in, const int* in_sizes, int n_in,
                              void* d_out, int out_size, void* d_ws, size_t ws_size,
                              hipStream_t stream) {
    const int*   text   = (const int*)  d_in[0];
    const float* emb    = (const float*)d_in[1];
    const float* conv_w = (const float*)d_in[2];
    const float* conv_b = (const float*)d_in[3];
    const float* U_w    = (const float*)d_in[4];
    const float* F_w    = (const float*)d_in[5];
    const float* f_b    = (const float*)d_in[6];
    float* out = (float*)d_out;

    char* ws = (char*)d_ws;
    unsigned short* xf  = (unsigned short*)ws; ws += (size_t)B * S * NK * 2;
    unsigned short* wtb = (unsigned short*)ws; ws += (size_t)KSZ * NK * D_MODEL * 2;
    unsigned short* Ub  = (unsigned short*)ws; ws += (size_t)NC * NK * 2;
    unsigned short* Fb  = (unsigned short*)ws; ws += (size_t)NC * NK * 2;
    float* pl = (float*)ws; ws += (size_t)SSPLIT * B * NC * 4;
    float* pg = (float*)ws; ws += (size_t)SSPLIT * B * NC * 4;

    prep_all<<<dim3((PREP_N + 255) / 256), 256, 0, stream>>>(conv_w, wtb, U_w, Ub, F_w, Fb);
    conv_mfma<<<dim3(B * S / CM), 512, 0, stream>>>(text, emb, wtb, conv_b, xf);
    attn_mfma<<<dim3(NC / 128, SSPLIT, B), 256, 0, stream>>>(xf, Ub, Fb, pl, pg);
    combine_kernel<<<dim3((B * NC + 255) / 256), 256, 0, stream>>>(pl, pg, f_b, out);
}